// Round 1
// baseline (1775.291 us; speedup 1.0000x reference)
//
#include <hip/hip_runtime.h>

static __device__ __forceinline__ float leaky(float v) {
    return v >= 0.0f ? v : 0.01f * v;
}

// ---- degree: deg[dst] += 1 over all edges ----
__global__ void k_deg(const int* __restrict__ dst, float* __restrict__ deg, int nE) {
    int e = blockIdx.x * blockDim.x + threadIdx.x;
    if (e < nE) atomicAdd(&deg[dst[e]], 1.0f);
}

// ---- dinv = rsqrt(deg + 1) in place ----
__global__ void k_dinv(float* __restrict__ dinv, int n) {
    int i = blockIdx.x * blockDim.x + threadIdx.x;
    if (i < n) dinv[i] = rsqrtf(dinv[i] + 1.0f);
}

// ---- h0 = emb[x] gather, elementwise over 3*nN ----
__global__ void k_h0(const int* __restrict__ x, const float* __restrict__ emb,
                     float* __restrict__ h0, int n3) {
    int i = blockIdx.x * blockDim.x + threadIdx.x;
    if (i < n3) {
        int node = i / 3, c = i - node * 3;
        h0[i] = emb[x[node] * 3 + c];
    }
}

// ---- 3-dim scatter: agg[dst] += h[src] * dinv[src]*dinv[dst] ----
__global__ void k_scatter3(const int* __restrict__ src, const int* __restrict__ dst,
                           const float* __restrict__ dinv, const float* __restrict__ h,
                           float* __restrict__ agg, int nE) {
    int e = blockIdx.x * blockDim.x + threadIdx.x;
    if (e >= nE) return;
    int s = src[e], d = dst[e];
    float w = dinv[s] * dinv[d];
    atomicAdd(&agg[d * 3 + 0], h[s * 3 + 0] * w);
    atomicAdd(&agg[d * 3 + 1], h[s * 3 + 1] * w);
    atomicAdd(&agg[d * 3 + 2], h[s * 3 + 2] * w);
}

// ---- layer-1 finalize: (agg0 + h0*dinv^2) @ W1 + b1 -> leaky -> @ W2 -> hW2 ----
__global__ void k_l1(const float* __restrict__ agg0, const float* __restrict__ h0,
                     const float* __restrict__ dinv,
                     const float* __restrict__ W1, const float* __restrict__ b1,
                     const float* __restrict__ W2,
                     float* __restrict__ hW2, int n) {
    int i = blockIdx.x * blockDim.x + threadIdx.x;
    if (i >= n) return;
    float di = dinv[i], d2 = di * di;
    float a0 = agg0[i * 3 + 0] + h0[i * 3 + 0] * d2;
    float a1 = agg0[i * 3 + 1] + h0[i * 3 + 1] * d2;
    float a2 = agg0[i * 3 + 2] + h0[i * 3 + 2] * d2;
    float o0 = 0.f, o1 = 0.f, o2 = 0.f;
#pragma unroll
    for (int k = 0; k < 16; ++k) {
        float p = leaky(a0 * W1[k] + a1 * W1[16 + k] + a2 * W1[32 + k] + b1[k]);
        o0 += p * W2[k * 3 + 0];
        o1 += p * W2[k * 3 + 1];
        o2 += p * W2[k * 3 + 2];
    }
    hW2[i * 3 + 0] = o0;
    hW2[i * 3 + 1] = o1;
    hW2[i * 3 + 2] = o2;
}

// ---- layer-2 finalize: h2 = leaky(agg2 + hW2*dinv^2 + b2) ----
__global__ void k_l2(const float* __restrict__ agg2, const float* __restrict__ hW2,
                     const float* __restrict__ dinv, const float* __restrict__ b2,
                     float* __restrict__ h2, int n) {
    int i = blockIdx.x * blockDim.x + threadIdx.x;
    if (i >= n) return;
    float di = dinv[i], d2 = di * di;
#pragma unroll
    for (int j = 0; j < 3; ++j)
        h2[i * 3 + j] = leaky(agg2[i * 3 + j] + hW2[i * 3 + j] * d2 + b2[j]);
}

// ---- per-match MLP: concat(h2[home],h2[away]) -> 16 -> 6 -> 3, leaky each ----
__global__ void k_mlp(const int* __restrict__ home, const int* __restrict__ away,
                      const float* __restrict__ h2,
                      const float* __restrict__ lw1, const float* __restrict__ lb1,
                      const float* __restrict__ lw2, const float* __restrict__ lb2,
                      const float* __restrict__ lw3, const float* __restrict__ lb3,
                      float* __restrict__ out, int nM) {
    __shared__ float s[235];
    int t = threadIdx.x;
    if (t < 96)       s[t] = lw1[t];
    else if (t < 112) s[t] = lb1[t - 96];
    else if (t < 208) s[t] = lw2[t - 112];
    else if (t < 214) s[t] = lb2[t - 208];
    else if (t < 232) s[t] = lw3[t - 214];
    else if (t < 235) s[t] = lb3[t - 232];
    __syncthreads();
    const float* sw1 = s;        const float* sb1 = s + 96;
    const float* sw2 = s + 112;  const float* sb2 = s + 208;
    const float* sw3 = s + 214;  const float* sb3 = s + 232;

    int m = blockIdx.x * blockDim.x + threadIdx.x;
    if (m >= nM) return;
    int hn = home[m], an = away[m];
    float z[6];
    z[0] = h2[hn * 3 + 0]; z[1] = h2[hn * 3 + 1]; z[2] = h2[hn * 3 + 2];
    z[3] = h2[an * 3 + 0]; z[4] = h2[an * 3 + 1]; z[5] = h2[an * 3 + 2];

    float t1[16];
#pragma unroll
    for (int k = 0; k < 16; ++k) {
        float p = sb1[k];
#pragma unroll
        for (int j = 0; j < 6; ++j) p += z[j] * sw1[j * 16 + k];
        t1[k] = leaky(p);
    }
    float t2[6];
#pragma unroll
    for (int k = 0; k < 6; ++k) {
        float p = sb2[k];
#pragma unroll
        for (int j = 0; j < 16; ++j) p += t1[j] * sw2[j * 6 + k];
        t2[k] = leaky(p);
    }
#pragma unroll
    for (int k = 0; k < 3; ++k) {
        float p = sb3[k];
#pragma unroll
        for (int j = 0; j < 6; ++j) p += t2[j] * sw3[j * 3 + k];
        out[m * 3 + k] = leaky(p);
    }
}

extern "C" void kernel_launch(void* const* d_in, const int* in_sizes, int n_in,
                              void* d_out, int out_size, void* d_ws, size_t ws_size,
                              hipStream_t stream) {
    const int*   x    = (const int*)d_in[0];
    const int*   ei   = (const int*)d_in[1];
    const int*   home = (const int*)d_in[2];
    const int*   away = (const int*)d_in[3];
    const float* emb  = (const float*)d_in[4];
    const float* W1   = (const float*)d_in[5];
    const float* b1   = (const float*)d_in[6];
    const float* W2   = (const float*)d_in[7];
    const float* b2   = (const float*)d_in[8];
    const float* lw1  = (const float*)d_in[9];
    const float* lb1  = (const float*)d_in[10];
    const float* lw2  = (const float*)d_in[11];
    const float* lb2  = (const float*)d_in[12];
    const float* lw3  = (const float*)d_in[13];
    const float* lb3  = (const float*)d_in[14];
    float* out = (float*)d_out;

    const int nN = in_sizes[0];       // 100000 nodes
    const int nE = in_sizes[1] / 2;   // 5M edges
    const int nM = in_sizes[2];       // 1M matches
    const int* src = ei;
    const int* dst = ei + nE;

    float* ws   = (float*)d_ws;
    float* dinv = ws;               // nN
    float* h0   = dinv + nN;        // 3*nN
    float* agg0 = h0 + 3 * nN;      // 3*nN
    float* hW2  = agg0 + 3 * nN;    // 3*nN
    float* agg2 = hW2 + 3 * nN;     // 3*nN
    float* h2   = agg2 + 3 * nN;    // 3*nN

    hipMemsetAsync(dinv, 0, (size_t)nN * sizeof(float), stream);
    hipMemsetAsync(agg0, 0, (size_t)3 * nN * sizeof(float), stream);
    hipMemsetAsync(agg2, 0, (size_t)3 * nN * sizeof(float), stream);

    const int B = 256;
    k_deg<<<(nE + B - 1) / B, B, 0, stream>>>(dst, dinv, nE);
    k_dinv<<<(nN + B - 1) / B, B, 0, stream>>>(dinv, nN);
    k_h0<<<(3 * nN + B - 1) / B, B, 0, stream>>>(x, emb, h0, 3 * nN);
    k_scatter3<<<(nE + B - 1) / B, B, 0, stream>>>(src, dst, dinv, h0, agg0, nE);
    k_l1<<<(nN + B - 1) / B, B, 0, stream>>>(agg0, h0, dinv, W1, b1, W2, hW2, nN);
    k_scatter3<<<(nE + B - 1) / B, B, 0, stream>>>(src, dst, dinv, hW2, agg2, nE);
    k_l2<<<(nN + B - 1) / B, B, 0, stream>>>(agg2, hW2, dinv, b2, h2, nN);
    k_mlp<<<(nM + B - 1) / B, B, 0, stream>>>(home, away, h2,
                                              lw1, lb1, lw2, lb2, lw3, lb3, out, nM);
}

// Round 2
// 735.483 us; speedup vs baseline: 2.4138x; 2.4138x over previous
//
#include <hip/hip_runtime.h>

static __device__ __forceinline__ float leaky(float v) {
    return v >= 0.0f ? v : 0.01f * v;
}

// ================= CSR build =================

__global__ void k_hist(const int* __restrict__ dst, int* __restrict__ cnt, int nE) {
    int e = blockIdx.x * blockDim.x + threadIdx.x;
    if (e < nE) atomicAdd(&cnt[dst[e]], 1);
}

#define SCAN_BLK 1024
// per-block exclusive scan chunk + block sums
__global__ void k_scanA(const int* __restrict__ cnt, int* __restrict__ off,
                        int* __restrict__ bsum, int nTot, int nN) {
    __shared__ int s[SCAN_BLK];
    int t = threadIdx.x;
    int i = blockIdx.x * SCAN_BLK + t;
    int v = (i < nN) ? cnt[i] : 0;
    s[t] = v;
    for (int o = 1; o < SCAN_BLK; o <<= 1) {
        __syncthreads();
        int x = (t >= o) ? s[t - o] : 0;
        __syncthreads();
        s[t] += x;
    }
    __syncthreads();
    int incl = s[t];
    if (i < nTot) off[i] = incl - v;           // exclusive within block
    if (t == SCAN_BLK - 1) bsum[blockIdx.x] = incl;
}

// scan the (<=128) block sums in one block
__global__ void k_scanB(int* __restrict__ bsum, int nb) {
    __shared__ int s[128];
    int t = threadIdx.x;
    int v = (t < nb) ? bsum[t] : 0;
    s[t] = v;
    for (int o = 1; o < 128; o <<= 1) {
        __syncthreads();
        int x = (t >= o) ? s[t - o] : 0;
        __syncthreads();
        s[t] += x;
    }
    __syncthreads();
    if (t < nb) bsum[t] = s[t] - v;            // exclusive
}

// add block offsets; emit dinv and cursor copy
__global__ void k_scanC(int* __restrict__ off, const int* __restrict__ bsum,
                        const int* __restrict__ cnt, float* __restrict__ dinv,
                        int* __restrict__ cur, int nTot, int nN) {
    int i = blockIdx.x * blockDim.x + threadIdx.x;
    if (i >= nTot) return;
    int o = off[i] + bsum[i / SCAN_BLK];
    off[i] = o;
    if (i < nN) {
        dinv[i] = rsqrtf((float)cnt[i] + 1.0f);
        cur[i] = o;
    }
}

__global__ void k_place(const int* __restrict__ src, const int* __restrict__ dst,
                        int* __restrict__ cur, int* __restrict__ csr, int nE) {
    int e = blockIdx.x * blockDim.x + threadIdx.x;
    if (e >= nE) return;
    int p = atomicAdd(&cur[dst[e]], 1);
    csr[p] = src[e];
}

// ================= node tables =================

// hd0[n] = emb[x[n]] * dinv[n]   (float4-padded)
__global__ void k_hd0(const int* __restrict__ x, const float* __restrict__ emb,
                      const float* __restrict__ dinv, float4* __restrict__ hd0, int nN) {
    int i = blockIdx.x * blockDim.x + threadIdx.x;
    if (i >= nN) return;
    float di = dinv[i];
    int xi = x[i] * 3;
    hd0[i] = make_float4(emb[xi] * di, emb[xi + 1] * di, emb[xi + 2] * di, 0.0f);
}

// ================= gathers (wave per node) =================

// layer1: a = dinv[d]*(sum_{s in N(d)} hd0[s] + hd0[d]); chain @W1+b1->leaky->@W2;
// hd2[d] = result * dinv[d]
__global__ void k_gather1(const int* __restrict__ off, const int* __restrict__ csr,
                          const float4* __restrict__ hd0, const float* __restrict__ dinv,
                          const float* __restrict__ W1, const float* __restrict__ b1,
                          const float* __restrict__ W2,
                          float4* __restrict__ hd2, int nN) {
    int g = blockIdx.x * blockDim.x + threadIdx.x;
    int d = g >> 6, lane = threadIdx.x & 63;
    if (d >= nN) return;
    int e0 = off[d], e1 = off[d + 1];
    float sx = 0.f, sy = 0.f, sz = 0.f;
    for (int e = e0 + lane; e < e1; e += 64) {
        float4 v = hd0[csr[e]];
        sx += v.x; sy += v.y; sz += v.z;
    }
    for (int o = 32; o; o >>= 1) {
        sx += __shfl_down(sx, o);
        sy += __shfl_down(sy, o);
        sz += __shfl_down(sz, o);
    }
    if (lane == 0) {
        float di = dinv[d];
        float4 self = hd0[d];
        float a0 = di * (sx + self.x);
        float a1 = di * (sy + self.y);
        float a2 = di * (sz + self.z);
        float o0 = 0.f, o1 = 0.f, o2 = 0.f;
#pragma unroll
        for (int k = 0; k < 16; ++k) {
            float p = leaky(a0 * W1[k] + a1 * W1[16 + k] + a2 * W1[32 + k] + b1[k]);
            o0 += p * W2[k * 3 + 0];
            o1 += p * W2[k * 3 + 1];
            o2 += p * W2[k * 3 + 2];
        }
        hd2[d] = make_float4(o0 * di, o1 * di, o2 * di, 0.0f);
    }
}

// layer2: h2[d] = leaky(dinv[d]*(sum hd2[s] + hd2[d]) + b2)
__global__ void k_gather2(const int* __restrict__ off, const int* __restrict__ csr,
                          const float4* __restrict__ hd2, const float* __restrict__ dinv,
                          const float* __restrict__ b2,
                          float4* __restrict__ h2, int nN) {
    int g = blockIdx.x * blockDim.x + threadIdx.x;
    int d = g >> 6, lane = threadIdx.x & 63;
    if (d >= nN) return;
    int e0 = off[d], e1 = off[d + 1];
    float sx = 0.f, sy = 0.f, sz = 0.f;
    for (int e = e0 + lane; e < e1; e += 64) {
        float4 v = hd2[csr[e]];
        sx += v.x; sy += v.y; sz += v.z;
    }
    for (int o = 32; o; o >>= 1) {
        sx += __shfl_down(sx, o);
        sy += __shfl_down(sy, o);
        sz += __shfl_down(sz, o);
    }
    if (lane == 0) {
        float di = dinv[d];
        float4 self = hd2[d];
        h2[d] = make_float4(leaky(di * (sx + self.x) + b2[0]),
                            leaky(di * (sy + self.y) + b2[1]),
                            leaky(di * (sz + self.z) + b2[2]), 0.0f);
    }
}

// ================= per-match MLP =================

__global__ void k_mlp4(const int* __restrict__ home, const int* __restrict__ away,
                       const float4* __restrict__ h2,
                       const float* __restrict__ lw1, const float* __restrict__ lb1,
                       const float* __restrict__ lw2, const float* __restrict__ lb2,
                       const float* __restrict__ lw3, const float* __restrict__ lb3,
                       float* __restrict__ out, int nM) {
    __shared__ float s[235];
    int t = threadIdx.x;
    if (t < 96)       s[t] = lw1[t];
    else if (t < 112) s[t] = lb1[t - 96];
    else if (t < 208) s[t] = lw2[t - 112];
    else if (t < 214) s[t] = lb2[t - 208];
    else if (t < 232) s[t] = lw3[t - 214];
    else if (t < 235) s[t] = lb3[t - 232];
    __syncthreads();
    const float* sw1 = s;        const float* sb1 = s + 96;
    const float* sw2 = s + 112;  const float* sb2 = s + 208;
    const float* sw3 = s + 214;  const float* sb3 = s + 232;

    int m = blockIdx.x * blockDim.x + threadIdx.x;
    if (m >= nM) return;
    float4 zh = h2[home[m]];
    float4 za = h2[away[m]];
    float z[6] = {zh.x, zh.y, zh.z, za.x, za.y, za.z};

    float t1[16];
#pragma unroll
    for (int k = 0; k < 16; ++k) {
        float p = sb1[k];
#pragma unroll
        for (int j = 0; j < 6; ++j) p += z[j] * sw1[j * 16 + k];
        t1[k] = leaky(p);
    }
    float t2[6];
#pragma unroll
    for (int k = 0; k < 6; ++k) {
        float p = sb2[k];
#pragma unroll
        for (int j = 0; j < 16; ++j) p += t1[j] * sw2[j * 6 + k];
        t2[k] = leaky(p);
    }
#pragma unroll
    for (int k = 0; k < 3; ++k) {
        float p = sb3[k];
#pragma unroll
        for (int j = 0; j < 6; ++j) p += t2[j] * sw3[j * 3 + k];
        out[m * 3 + k] = leaky(p);
    }
}

// ================= fallback (push-scatter, small ws) =================

__global__ void k_deg(const int* __restrict__ dst, float* __restrict__ deg, int nE) {
    int e = blockIdx.x * blockDim.x + threadIdx.x;
    if (e < nE) atomicAdd(&deg[dst[e]], 1.0f);
}
__global__ void k_dinv(float* __restrict__ dinv, int n) {
    int i = blockIdx.x * blockDim.x + threadIdx.x;
    if (i < n) dinv[i] = rsqrtf(dinv[i] + 1.0f);
}
__global__ void k_h0(const int* __restrict__ x, const float* __restrict__ emb,
                     float* __restrict__ h0, int n3) {
    int i = blockIdx.x * blockDim.x + threadIdx.x;
    if (i < n3) { int node = i / 3, c = i - node * 3; h0[i] = emb[x[node] * 3 + c]; }
}
__global__ void k_scatter3(const int* __restrict__ src, const int* __restrict__ dst,
                           const float* __restrict__ dinv, const float* __restrict__ h,
                           float* __restrict__ agg, int nE) {
    int e = blockIdx.x * blockDim.x + threadIdx.x;
    if (e >= nE) return;
    int s = src[e], d = dst[e];
    float w = dinv[s] * dinv[d];
    atomicAdd(&agg[d * 3 + 0], h[s * 3 + 0] * w);
    atomicAdd(&agg[d * 3 + 1], h[s * 3 + 1] * w);
    atomicAdd(&agg[d * 3 + 2], h[s * 3 + 2] * w);
}
__global__ void k_l1(const float* __restrict__ agg0, const float* __restrict__ h0,
                     const float* __restrict__ dinv,
                     const float* __restrict__ W1, const float* __restrict__ b1,
                     const float* __restrict__ W2,
                     float* __restrict__ hW2, int n) {
    int i = blockIdx.x * blockDim.x + threadIdx.x;
    if (i >= n) return;
    float di = dinv[i], d2 = di * di;
    float a0 = agg0[i * 3 + 0] + h0[i * 3 + 0] * d2;
    float a1 = agg0[i * 3 + 1] + h0[i * 3 + 1] * d2;
    float a2 = agg0[i * 3 + 2] + h0[i * 3 + 2] * d2;
    float o0 = 0.f, o1 = 0.f, o2 = 0.f;
#pragma unroll
    for (int k = 0; k < 16; ++k) {
        float p = leaky(a0 * W1[k] + a1 * W1[16 + k] + a2 * W1[32 + k] + b1[k]);
        o0 += p * W2[k * 3 + 0]; o1 += p * W2[k * 3 + 1]; o2 += p * W2[k * 3 + 2];
    }
    hW2[i * 3 + 0] = o0; hW2[i * 3 + 1] = o1; hW2[i * 3 + 2] = o2;
}
__global__ void k_l2(const float* __restrict__ agg2, const float* __restrict__ hW2,
                     const float* __restrict__ dinv, const float* __restrict__ b2,
                     float* __restrict__ h2, int n) {
    int i = blockIdx.x * blockDim.x + threadIdx.x;
    if (i >= n) return;
    float di = dinv[i], d2 = di * di;
#pragma unroll
    for (int j = 0; j < 3; ++j)
        h2[i * 3 + j] = leaky(agg2[i * 3 + j] + hW2[i * 3 + j] * d2 + b2[j]);
}
__global__ void k_mlp3(const int* __restrict__ home, const int* __restrict__ away,
                       const float* __restrict__ h2,
                       const float* __restrict__ lw1, const float* __restrict__ lb1,
                       const float* __restrict__ lw2, const float* __restrict__ lb2,
                       const float* __restrict__ lw3, const float* __restrict__ lb3,
                       float* __restrict__ out, int nM) {
    __shared__ float s[235];
    int t = threadIdx.x;
    if (t < 96)       s[t] = lw1[t];
    else if (t < 112) s[t] = lb1[t - 96];
    else if (t < 208) s[t] = lw2[t - 112];
    else if (t < 214) s[t] = lb2[t - 208];
    else if (t < 232) s[t] = lw3[t - 214];
    else if (t < 235) s[t] = lb3[t - 232];
    __syncthreads();
    const float* sw1 = s;        const float* sb1 = s + 96;
    const float* sw2 = s + 112;  const float* sb2 = s + 208;
    const float* sw3 = s + 214;  const float* sb3 = s + 232;
    int m = blockIdx.x * blockDim.x + threadIdx.x;
    if (m >= nM) return;
    int hn = home[m], an = away[m];
    float z[6] = {h2[hn*3], h2[hn*3+1], h2[hn*3+2], h2[an*3], h2[an*3+1], h2[an*3+2]};
    float t1[16];
#pragma unroll
    for (int k = 0; k < 16; ++k) {
        float p = sb1[k];
#pragma unroll
        for (int j = 0; j < 6; ++j) p += z[j] * sw1[j * 16 + k];
        t1[k] = leaky(p);
    }
    float t2[6];
#pragma unroll
    for (int k = 0; k < 6; ++k) {
        float p = sb2[k];
#pragma unroll
        for (int j = 0; j < 16; ++j) p += t1[j] * sw2[j * 6 + k];
        t2[k] = leaky(p);
    }
#pragma unroll
    for (int k = 0; k < 3; ++k) {
        float p = sb3[k];
#pragma unroll
        for (int j = 0; j < 6; ++j) p += t2[j] * sw3[j * 3 + k];
        out[m * 3 + k] = leaky(p);
    }
}

// ================= launch =================

extern "C" void kernel_launch(void* const* d_in, const int* in_sizes, int n_in,
                              void* d_out, int out_size, void* d_ws, size_t ws_size,
                              hipStream_t stream) {
    const int*   x    = (const int*)d_in[0];
    const int*   ei   = (const int*)d_in[1];
    const int*   home = (const int*)d_in[2];
    const int*   away = (const int*)d_in[3];
    const float* emb  = (const float*)d_in[4];
    const float* W1   = (const float*)d_in[5];
    const float* b1   = (const float*)d_in[6];
    const float* W2   = (const float*)d_in[7];
    const float* b2   = (const float*)d_in[8];
    const float* lw1  = (const float*)d_in[9];
    const float* lb1  = (const float*)d_in[10];
    const float* lw2  = (const float*)d_in[11];
    const float* lb2  = (const float*)d_in[12];
    const float* lw3  = (const float*)d_in[13];
    const float* lb3  = (const float*)d_in[14];
    float* out = (float*)d_out;

    const int nN = in_sizes[0];       // 100000
    const int nE = in_sizes[1] / 2;   // 5M
    const int nM = in_sizes[2];       // 1M
    const int* src = ei;
    const int* dst = ei + nE;
    const int B = 256;

    // workspace layout (16B-aligned blocks first)
    size_t need = (size_t)3 * nN * 16 + (size_t)nE * 4 + (size_t)nN * 4 * 4 +
                  (size_t)(nN + 1) * 4 + 128 * 4;
    if (ws_size >= need) {
        char* w = (char*)d_ws;
        float4* hd0 = (float4*)w;                 w += (size_t)nN * 16;
        float4* hd2 = (float4*)w;                 w += (size_t)nN * 16;
        float4* h2  = (float4*)w;                 w += (size_t)nN * 16;
        int* csr  = (int*)w;                      w += (size_t)nE * 4;
        int* cnt  = (int*)w;                      w += (size_t)nN * 4;
        int* off  = (int*)w;                      w += (size_t)(nN + 1) * 4;
        int* cur  = (int*)w;                      w += (size_t)nN * 4;
        int* bsum = (int*)w;                      w += 128 * 4;
        float* dinv = (float*)w;

        const int nTot = nN + 1;
        const int nbScan = (nTot + SCAN_BLK - 1) / SCAN_BLK;   // 98

        hipMemsetAsync(cnt, 0, (size_t)nN * sizeof(int), stream);
        k_hist<<<(nE + B - 1) / B, B, 0, stream>>>(dst, cnt, nE);
        k_scanA<<<nbScan, SCAN_BLK, 0, stream>>>(cnt, off, bsum, nTot, nN);
        k_scanB<<<1, 128, 0, stream>>>(bsum, nbScan);
        k_scanC<<<(nTot + B - 1) / B, B, 0, stream>>>(off, bsum, cnt, dinv, cur, nTot, nN);
        k_hd0<<<(nN + B - 1) / B, B, 0, stream>>>(x, emb, dinv, hd0, nN);
        k_place<<<(nE + B - 1) / B, B, 0, stream>>>(src, dst, cur, csr, nE);
        k_gather1<<<(nN * 64 + B - 1) / B, B, 0, stream>>>(off, csr, hd0, dinv,
                                                           W1, b1, W2, hd2, nN);
        k_gather2<<<(nN * 64 + B - 1) / B, B, 0, stream>>>(off, csr, hd2, dinv,
                                                           b2, h2, nN);
        k_mlp4<<<(nM + B - 1) / B, B, 0, stream>>>(home, away, h2,
                                                   lw1, lb1, lw2, lb2, lw3, lb3, out, nM);
    } else {
        // fallback: push-scatter (round-1 path)
        float* ws   = (float*)d_ws;
        float* dinv = ws;
        float* h0   = dinv + nN;
        float* agg0 = h0 + 3 * nN;
        float* hW2  = agg0 + 3 * nN;
        float* agg2 = hW2 + 3 * nN;
        float* h2   = agg2 + 3 * nN;
        hipMemsetAsync(dinv, 0, (size_t)nN * sizeof(float), stream);
        hipMemsetAsync(agg0, 0, (size_t)3 * nN * sizeof(float), stream);
        hipMemsetAsync(agg2, 0, (size_t)3 * nN * sizeof(float), stream);
        k_deg<<<(nE + B - 1) / B, B, 0, stream>>>(dst, dinv, nE);
        k_dinv<<<(nN + B - 1) / B, B, 0, stream>>>(dinv, nN);
        k_h0<<<(3 * nN + B - 1) / B, B, 0, stream>>>(x, emb, h0, 3 * nN);
        k_scatter3<<<(nE + B - 1) / B, B, 0, stream>>>(src, dst, dinv, h0, agg0, nE);
        k_l1<<<(nN + B - 1) / B, B, 0, stream>>>(agg0, h0, dinv, W1, b1, W2, hW2, nN);
        k_scatter3<<<(nE + B - 1) / B, B, 0, stream>>>(src, dst, dinv, hW2, agg2, nE);
        k_l2<<<(nN + B - 1) / B, B, 0, stream>>>(agg2, hW2, dinv, b2, h2, nN);
        k_mlp3<<<(nM + B - 1) / B, B, 0, stream>>>(home, away, h2,
                                                   lw1, lb1, lw2, lb2, lw3, lb3, out, nM);
    }
}

// Round 3
// 191.287 us; speedup vs baseline: 9.2808x; 3.8449x over previous
//
#include <hip/hip_runtime.h>

typedef unsigned int u32;
typedef unsigned long long u64;

static __device__ __forceinline__ float leaky(float v) {
    return v >= 0.0f ? v : 0.01f * v;
}

#define P1_CHUNK 4096
#define P1_T 256
#define NBK 512            // buckets = dst>>8  (requires nN <= 131072)
#define P2_T 256
#define P2_CAP 14336       // max bucket size for LDS-staged path (~+46 sigma)
#define SBLK 1024

// ================= pass 1: bucket histogram =================
__global__ void k_p1hist(const int* __restrict__ dst, int* __restrict__ gh,
                         int nE, int nb) {
    __shared__ int hist[NBK];
    int t = threadIdx.x;
    for (int b = t; b < NBK; b += P1_T) hist[b] = 0;
    __syncthreads();
    int base = blockIdx.x * P1_CHUNK;
    int lim = min(P1_CHUNK, nE - base);
    for (int i = t; i < lim; i += P1_T)
        atomicAdd(&hist[dst[base + i] >> 8], 1);
    __syncthreads();
    for (int b = t; b < NBK; b += P1_T)
        gh[b * nb + blockIdx.x] = hist[b];
}

// ================= generic scan (exclusive), in-place safe =================
__global__ void g_scanA(const int* __restrict__ in, int* __restrict__ out,
                        int* __restrict__ bsum, int n) {
    __shared__ int s[SBLK];
    int t = threadIdx.x, i = blockIdx.x * SBLK + t;
    int v = (i < n) ? in[i] : 0;
    s[t] = v;
    for (int o = 1; o < SBLK; o <<= 1) {
        __syncthreads();
        int x = (t >= o) ? s[t - o] : 0;
        __syncthreads();
        s[t] += x;
    }
    __syncthreads();
    if (i < n) out[i] = s[t] - v;
    if (t == SBLK - 1) bsum[blockIdx.x] = s[t];
}
__global__ void g_scanB(int* __restrict__ bsum, int nb) {
    __shared__ int s[SBLK];
    int t = threadIdx.x;
    int v = (t < nb) ? bsum[t] : 0;
    s[t] = v;
    for (int o = 1; o < SBLK; o <<= 1) {
        __syncthreads();
        int x = (t >= o) ? s[t - o] : 0;
        __syncthreads();
        s[t] += x;
    }
    __syncthreads();
    if (t < nb) bsum[t] = s[t] - v;
}
__global__ void g_scanC(int* __restrict__ out, const int* __restrict__ bsum, int n) {
    int i = blockIdx.x * blockDim.x + threadIdx.x;
    if (i < n) out[i] += bsum[i / SBLK];
}

// ================= pass 1: ranked scatter into buckets (coalesced runs) ====
__global__ void k_p1scatter(const int* __restrict__ src, const int* __restrict__ dst,
                            const int* __restrict__ gh, u32* __restrict__ bkt,
                            int nE, int nb) {
    __shared__ int hist[NBK];    // counts -> inclusive scan -> cursor
    __shared__ int loff[NBK];
    __shared__ int gb[NBK];
    __shared__ u64 stg[P1_CHUNK];
    int t = threadIdx.x;
    for (int b = t; b < NBK; b += P1_T) hist[b] = 0;
    __syncthreads();
    int base = blockIdx.x * P1_CHUNK;
    int lim = min(P1_CHUNK, nE - base);
    for (int i = t; i < lim; i += P1_T)
        atomicAdd(&hist[dst[base + i] >> 8], 1);
    __syncthreads();
    int c0 = hist[t], c1 = hist[t + 256];
    for (int o = 1; o < NBK; o <<= 1) {
        __syncthreads();
        int a0 = (t >= o) ? hist[t - o] : 0;
        int a1 = (t + 256 >= o) ? hist[t + 256 - o] : 0;
        __syncthreads();
        hist[t] += a0; hist[t + 256] += a1;
    }
    __syncthreads();
    loff[t] = hist[t] - c0;
    loff[t + 256] = hist[t + 256] - c1;
    hist[t] = loff[t];               // cursor = local exclusive offset
    hist[t + 256] = loff[t + 256];
    gb[t] = gh[t * nb + blockIdx.x];             // global base per bucket
    gb[t + 256] = gh[(t + 256) * nb + blockIdx.x];
    __syncthreads();
    for (int i = t; i < lim; i += P1_T) {        // rank & stage (bin-sorted)
        int d = dst[base + i];
        int s = src[base + i];
        int b = d >> 8;
        int r = atomicAdd(&hist[b], 1);
        stg[r] = ((u64)b << 32) | (u32)(((d & 255) << 17) | s);
    }
    __syncthreads();
    for (int i = t; i < lim; i += P1_T) {        // coalesced-run write-out
        u64 v = stg[i];
        int b = (int)(v >> 32);
        bkt[gb[b] + (i - loff[b])] = (u32)v;
    }
}

// ===== pass 2: per-bucket counting sort == CSR build; emits off/dinv =======
__global__ void k_p2(const u32* bkt, const int* __restrict__ gh,
                     int* csr, int* __restrict__ off, float* __restrict__ dinv,
                     int nE, int nb, int nN) {
    __shared__ int hist[256];
    __shared__ int loff[256];
    __shared__ int stg[P2_CAP];
    int t = threadIdx.x;
    int b = blockIdx.x;
    int base = gh[b * nb];
    int end  = (b + 1 < NBK) ? gh[(b + 1) * nb] : nE;
    int sz = end - base;
    hist[t] = 0;
    __syncthreads();
    for (int i = t; i < sz; i += P2_T)
        atomicAdd(&hist[bkt[base + i] >> 17], 1);
    __syncthreads();
    int c = hist[t];
    for (int o = 1; o < 256; o <<= 1) {
        __syncthreads();
        int a = (t >= o) ? hist[t - o] : 0;
        __syncthreads();
        hist[t] += a;
    }
    __syncthreads();
    int lo = hist[t] - c;
    loff[t] = lo;
    int d = b * 256 + t;                 // (bucket,bin) uniquely identifies dst
    off[d] = base + lo;
    if (d < nN) dinv[d] = rsqrtf((float)c + 1.0f);
    if (b == NBK - 1 && t == 255) off[NBK * 256] = nE;
    hist[t] = lo;                        // cursor
    __syncthreads();
    if (sz <= P2_CAP) {
        for (int i = t; i < sz; i += P2_T) {
            u32 v = bkt[base + i];
            int r = atomicAdd(&hist[v >> 17], 1);
            stg[r] = (int)(v & 0x1FFFF);
        }
        __syncthreads();                 // all reads done before in-place writes
        for (int i = t; i < sz; i += P2_T)
            csr[base + i] = stg[i];
    } else {                             // statistically unreachable fallback
        for (int i = t; i < sz; i += P2_T) {
            u32 v = bkt[base + i];
            int r = atomicAdd(&hist[v >> 17], 1);
            csr[base + r] = (int)(v & 0x1FFFF);
        }
    }
}

// ================= node tables =================
__global__ void k_hd0(const int* __restrict__ x, const float* __restrict__ emb,
                      const float* __restrict__ dinv, float4* __restrict__ hd0, int nN) {
    int i = blockIdx.x * blockDim.x + threadIdx.x;
    if (i >= nN) return;
    float di = dinv[i];
    int xi = x[i] * 3;
    hd0[i] = make_float4(emb[xi] * di, emb[xi + 1] * di, emb[xi + 2] * di, 0.0f);
}

// ================= gathers (wave per node) =================
__global__ void k_gather1(const int* __restrict__ off, const int* __restrict__ csr,
                          const float4* __restrict__ hd0, const float* __restrict__ dinv,
                          const float* __restrict__ W1, const float* __restrict__ b1,
                          const float* __restrict__ W2,
                          float4* __restrict__ hd2, int nN) {
    int g = blockIdx.x * blockDim.x + threadIdx.x;
    int d = g >> 6, lane = threadIdx.x & 63;
    if (d >= nN) return;
    int e0 = off[d], e1 = off[d + 1];
    float sx = 0.f, sy = 0.f, sz = 0.f;
    for (int e = e0 + lane; e < e1; e += 64) {
        float4 v = hd0[csr[e]];
        sx += v.x; sy += v.y; sz += v.z;
    }
    for (int o = 32; o; o >>= 1) {
        sx += __shfl_down(sx, o);
        sy += __shfl_down(sy, o);
        sz += __shfl_down(sz, o);
    }
    if (lane == 0) {
        float di = dinv[d];
        float4 self = hd0[d];
        float a0 = di * (sx + self.x);
        float a1 = di * (sy + self.y);
        float a2 = di * (sz + self.z);
        float o0 = 0.f, o1 = 0.f, o2 = 0.f;
#pragma unroll
        for (int k = 0; k < 16; ++k) {
            float p = leaky(a0 * W1[k] + a1 * W1[16 + k] + a2 * W1[32 + k] + b1[k]);
            o0 += p * W2[k * 3 + 0];
            o1 += p * W2[k * 3 + 1];
            o2 += p * W2[k * 3 + 2];
        }
        hd2[d] = make_float4(o0 * di, o1 * di, o2 * di, 0.0f);
    }
}

__global__ void k_gather2(const int* __restrict__ off, const int* __restrict__ csr,
                          const float4* __restrict__ hd2, const float* __restrict__ dinv,
                          const float* __restrict__ b2,
                          float4* __restrict__ h2, int nN) {
    int g = blockIdx.x * blockDim.x + threadIdx.x;
    int d = g >> 6, lane = threadIdx.x & 63;
    if (d >= nN) return;
    int e0 = off[d], e1 = off[d + 1];
    float sx = 0.f, sy = 0.f, sz = 0.f;
    for (int e = e0 + lane; e < e1; e += 64) {
        float4 v = hd2[csr[e]];
        sx += v.x; sy += v.y; sz += v.z;
    }
    for (int o = 32; o; o >>= 1) {
        sx += __shfl_down(sx, o);
        sy += __shfl_down(sy, o);
        sz += __shfl_down(sz, o);
    }
    if (lane == 0) {
        float di = dinv[d];
        float4 self = hd2[d];
        h2[d] = make_float4(leaky(di * (sx + self.x) + b2[0]),
                            leaky(di * (sy + self.y) + b2[1]),
                            leaky(di * (sz + self.z) + b2[2]), 0.0f);
    }
}

// ================= per-match MLP =================
__global__ void k_mlp4(const int* __restrict__ home, const int* __restrict__ away,
                       const float4* __restrict__ h2,
                       const float* __restrict__ lw1, const float* __restrict__ lb1,
                       const float* __restrict__ lw2, const float* __restrict__ lb2,
                       const float* __restrict__ lw3, const float* __restrict__ lb3,
                       float* __restrict__ out, int nM) {
    __shared__ float s[235];
    int t = threadIdx.x;
    if (t < 96)       s[t] = lw1[t];
    else if (t < 112) s[t] = lb1[t - 96];
    else if (t < 208) s[t] = lw2[t - 112];
    else if (t < 214) s[t] = lb2[t - 208];
    else if (t < 232) s[t] = lw3[t - 214];
    else if (t < 235) s[t] = lb3[t - 232];
    __syncthreads();
    const float* sw1 = s;        const float* sb1 = s + 96;
    const float* sw2 = s + 112;  const float* sb2 = s + 208;
    const float* sw3 = s + 214;  const float* sb3 = s + 232;

    int m = blockIdx.x * blockDim.x + threadIdx.x;
    if (m >= nM) return;
    float4 zh = h2[home[m]];
    float4 za = h2[away[m]];
    float z[6] = {zh.x, zh.y, zh.z, za.x, za.y, za.z};

    float t1[16];
#pragma unroll
    for (int k = 0; k < 16; ++k) {
        float p = sb1[k];
#pragma unroll
        for (int j = 0; j < 6; ++j) p += z[j] * sw1[j * 16 + k];
        t1[k] = leaky(p);
    }
    float t2[6];
#pragma unroll
    for (int k = 0; k < 6; ++k) {
        float p = sb2[k];
#pragma unroll
        for (int j = 0; j < 16; ++j) p += t1[j] * sw2[j * 6 + k];
        t2[k] = leaky(p);
    }
#pragma unroll
    for (int k = 0; k < 3; ++k) {
        float p = sb3[k];
#pragma unroll
        for (int j = 0; j < 6; ++j) p += t2[j] * sw3[j * 3 + k];
        out[m * 3 + k] = leaky(p);
    }
}

// ================= fallback: atomic CSR build (round-2 path) ===============
__global__ void k_hist(const int* __restrict__ dst, int* __restrict__ cnt, int nE) {
    int e = blockIdx.x * blockDim.x + threadIdx.x;
    if (e < nE) atomicAdd(&cnt[dst[e]], 1);
}
__global__ void k_prep(const int* __restrict__ off, const int* __restrict__ cnt,
                       float* __restrict__ dinv, int* __restrict__ cur, int nN) {
    int i = blockIdx.x * blockDim.x + threadIdx.x;
    if (i >= nN) return;
    dinv[i] = rsqrtf((float)cnt[i] + 1.0f);
    cur[i] = off[i];
}
__global__ void k_place(const int* __restrict__ src, const int* __restrict__ dst,
                        int* __restrict__ cur, int* __restrict__ csr, int nE) {
    int e = blockIdx.x * blockDim.x + threadIdx.x;
    if (e >= nE) return;
    int p = atomicAdd(&cur[dst[e]], 1);
    csr[p] = src[e];
}

// ================= launch =================
extern "C" void kernel_launch(void* const* d_in, const int* in_sizes, int n_in,
                              void* d_out, int out_size, void* d_ws, size_t ws_size,
                              hipStream_t stream) {
    const int*   x    = (const int*)d_in[0];
    const int*   ei   = (const int*)d_in[1];
    const int*   home = (const int*)d_in[2];
    const int*   away = (const int*)d_in[3];
    const float* emb  = (const float*)d_in[4];
    const float* W1   = (const float*)d_in[5];
    const float* b1   = (const float*)d_in[6];
    const float* W2   = (const float*)d_in[7];
    const float* b2   = (const float*)d_in[8];
    const float* lw1  = (const float*)d_in[9];
    const float* lb1  = (const float*)d_in[10];
    const float* lw2  = (const float*)d_in[11];
    const float* lb2  = (const float*)d_in[12];
    const float* lw3  = (const float*)d_in[13];
    const float* lb3  = (const float*)d_in[14];
    float* out = (float*)d_out;

    const int nN = in_sizes[0];       // 100000
    const int nE = in_sizes[1] / 2;   // 5M
    const int nM = in_sizes[2];       // 1M
    const int* src = ei;
    const int* dst = ei + nE;
    const int B = 256;

    const int nb1 = (nE + P1_CHUNK - 1) / P1_CHUNK;          // pass-1 blocks
    const int ghN = NBK * nb1;                                // gh entries
    const int nbs = (ghN + SBLK - 1) / SBLK;                  // scan blocks
    const int offN = NBK * 256 + 1;

    size_t base_need = (size_t)3 * nN * 16 + (size_t)nE * 4 + (size_t)ghN * 4 +
                       (size_t)offN * 4 + (size_t)nN * 4 + (size_t)(nbs + 8) * 4;
    size_t big_need  = base_need + (size_t)nE * 4;            // separate bkt

    if (nN <= NBK * 256 && ws_size >= base_need && nbs <= SBLK) {
        char* w = (char*)d_ws;
        float4* hd0 = (float4*)w;                 w += (size_t)nN * 16;
        float4* hd2 = (float4*)w;                 w += (size_t)nN * 16;
        float4* h2  = (float4*)w;                 w += (size_t)nN * 16;
        int* csr  = (int*)w;                      w += (size_t)nE * 4;
        int* gh   = (int*)w;                      w += (size_t)ghN * 4;
        int* off  = (int*)w;                      w += (size_t)offN * 4;
        float* dinv = (float*)w;                  w += (size_t)nN * 4;
        int* bsum = (int*)w;                      w += (size_t)(nbs + 8) * 4;
        u32* bkt = (ws_size >= big_need) ? (u32*)w : (u32*)csr;  // in-place OK

        k_p1hist<<<nb1, P1_T, 0, stream>>>(dst, gh, nE, nb1);
        g_scanA<<<nbs, SBLK, 0, stream>>>(gh, gh, bsum, ghN);
        g_scanB<<<1, SBLK, 0, stream>>>(bsum, nbs);
        g_scanC<<<(ghN + B - 1) / B, B, 0, stream>>>(gh, bsum, ghN);
        k_p1scatter<<<nb1, P1_T, 0, stream>>>(src, dst, gh, bkt, nE, nb1);
        k_p2<<<NBK, P2_T, 0, stream>>>(bkt, gh, csr, off, dinv, nE, nb1, nN);
        k_hd0<<<(nN + B - 1) / B, B, 0, stream>>>(x, emb, dinv, hd0, nN);
        k_gather1<<<((size_t)nN * 64 + B - 1) / B, B, 0, stream>>>(off, csr, hd0, dinv,
                                                                   W1, b1, W2, hd2, nN);
        k_gather2<<<((size_t)nN * 64 + B - 1) / B, B, 0, stream>>>(off, csr, hd2, dinv,
                                                                   b2, h2, nN);
        k_mlp4<<<(nM + B - 1) / B, B, 0, stream>>>(home, away, h2,
                                                   lw1, lb1, lw2, lb2, lw3, lb3, out, nM);
    } else {
        // fallback: atomic CSR build (round-2 path)
        char* w = (char*)d_ws;
        float4* hd0 = (float4*)w;                 w += (size_t)nN * 16;
        float4* hd2 = (float4*)w;                 w += (size_t)nN * 16;
        float4* h2  = (float4*)w;                 w += (size_t)nN * 16;
        int* csr  = (int*)w;                      w += (size_t)nE * 4;
        int* cnt  = (int*)w;                      w += (size_t)(nN + 1) * 4;
        int* off  = (int*)w;                      w += (size_t)(nN + 1) * 4;
        int* cur  = (int*)w;                      w += (size_t)nN * 4;
        float* dinv = (float*)w;                  w += (size_t)nN * 4;
        int* bsum = (int*)w;

        const int nTot = nN + 1;
        const int nbScan = (nTot + SBLK - 1) / SBLK;

        hipMemsetAsync(cnt, 0, (size_t)nTot * sizeof(int), stream);
        k_hist<<<(nE + B - 1) / B, B, 0, stream>>>(dst, cnt, nE);
        g_scanA<<<nbScan, SBLK, 0, stream>>>(cnt, off, bsum, nTot);
        g_scanB<<<1, SBLK, 0, stream>>>(bsum, nbScan);
        g_scanC<<<(nTot + B - 1) / B, B, 0, stream>>>(off, bsum, nTot);
        k_prep<<<(nN + B - 1) / B, B, 0, stream>>>(off, cnt, dinv, cur, nN);
        k_hd0<<<(nN + B - 1) / B, B, 0, stream>>>(x, emb, dinv, hd0, nN);
        k_place<<<(nE + B - 1) / B, B, 0, stream>>>(src, dst, cur, csr, nE);
        k_gather1<<<((size_t)nN * 64 + B - 1) / B, B, 0, stream>>>(off, csr, hd0, dinv,
                                                                   W1, b1, W2, hd2, nN);
        k_gather2<<<((size_t)nN * 64 + B - 1) / B, B, 0, stream>>>(off, csr, hd2, dinv,
                                                                   b2, h2, nN);
        k_mlp4<<<(nM + B - 1) / B, B, 0, stream>>>(home, away, h2,
                                                   lw1, lb1, lw2, lb2, lw3, lb3, out, nM);
    }
}

// Round 4
// 160.822 us; speedup vs baseline: 11.0388x; 1.1894x over previous
//
#include <hip/hip_runtime.h>

typedef unsigned int u32;
typedef unsigned short u16;

static __device__ __forceinline__ float leaky(float v) {
    return v >= 0.0f ? v : 0.01f * v;
}

#define P1_CHUNK 4096
#define P1_T 256
#define NBK 512            // buckets = dst>>8  (requires nN <= 131072)
#define P2_T 256
#define P2_CAP 14336       // max bucket size for LDS-staged path (mean 12800, +13 sigma)
#define SBLK 1024

// ================= pass 1: bucket histogram (bin-major gh) =================
__global__ void k_p1hist(const int* __restrict__ dst, int* __restrict__ gh,
                         int nE, int nb) {
    __shared__ int hist[NBK];
    int t = threadIdx.x;
    hist[t] = 0; hist[t + 256] = 0;
    __syncthreads();
    int base = blockIdx.x * P1_CHUNK;
    int lim = min(P1_CHUNK, nE - base);
    for (int i = t; i < lim; i += P1_T)
        atomicAdd(&hist[dst[base + i] >> 8], 1);
    __syncthreads();
    gh[t * nb + blockIdx.x] = hist[t];
    gh[(t + 256) * nb + blockIdx.x] = hist[t + 256];
}

// ================= generic scan (exclusive), in-place safe =================
__global__ void g_scanA(const int* __restrict__ in, int* __restrict__ out,
                        int* __restrict__ bsum, int n) {
    __shared__ int s[SBLK];
    int t = threadIdx.x, i = blockIdx.x * SBLK + t;
    int v = (i < n) ? in[i] : 0;
    s[t] = v;
    for (int o = 1; o < SBLK; o <<= 1) {
        __syncthreads();
        int x = (t >= o) ? s[t - o] : 0;
        __syncthreads();
        s[t] += x;
    }
    __syncthreads();
    if (i < n) out[i] = s[t] - v;
    if (t == SBLK - 1) bsum[blockIdx.x] = s[t];
}
__global__ void g_scanB(int* __restrict__ bsum, int nb) {
    __shared__ int s[SBLK];
    int t = threadIdx.x;
    int v = (t < nb) ? bsum[t] : 0;
    s[t] = v;
    for (int o = 1; o < SBLK; o <<= 1) {
        __syncthreads();
        int x = (t >= o) ? s[t - o] : 0;
        __syncthreads();
        s[t] += x;
    }
    __syncthreads();
    if (t < nb) bsum[t] = s[t] - v;
}
__global__ void g_scanC(int* __restrict__ out, const int* __restrict__ bsum,
                        int n, int total) {
    int i = blockIdx.x * blockDim.x + threadIdx.x;
    if (i < n) out[i] += bsum[i / SBLK];
    if (i == 0) out[n] = total;           // sentinel gh[ghN] = nE
}

// ====== pass 1 scatter: single edge pass, counts from scanned gh diffs =====
__global__ void k_p1scatter(const int* __restrict__ src, const int* __restrict__ dst,
                            const int* __restrict__ gh, u32* __restrict__ bkt,
                            int nE, int nb) {
    __shared__ int cur[NBK];
    __shared__ int loff[NBK];
    __shared__ int gb[NBK];
    __shared__ int sc[NBK];
    __shared__ u32 pay[P1_CHUNK];
    __shared__ u16 bb[P1_CHUNK];
    int t = threadIdx.x;
    int blk = blockIdx.x;
    int idx0 = t * nb + blk;
    int idx1 = (t + 256) * nb + blk;
    int g0 = gh[idx0], c0 = gh[idx0 + 1] - g0;
    int g1 = gh[idx1], c1 = gh[idx1 + 1] - g1;
    gb[t] = g0; gb[t + 256] = g1;
    sc[t] = c0; sc[t + 256] = c1;
    for (int o = 1; o < NBK; o <<= 1) {
        __syncthreads();
        int a0 = (t >= o) ? sc[t - o] : 0;
        int a1 = (t + 256 >= o) ? sc[t + 256 - o] : 0;
        __syncthreads();
        sc[t] += a0; sc[t + 256] += a1;
    }
    __syncthreads();
    loff[t] = sc[t] - c0;           loff[t + 256] = sc[t + 256] - c1;
    cur[t] = loff[t];               cur[t + 256] = loff[t + 256];
    __syncthreads();
    int base = blk * P1_CHUNK;
    int lim = min(P1_CHUNK, nE - base);
    for (int i = t; i < lim; i += P1_T) {
        int d = dst[base + i], s = src[base + i];
        int b = d >> 8;
        int r = atomicAdd(&cur[b], 1);
        pay[r] = (u32)(((d & 255) << 17) | s);
        bb[r] = (u16)b;
    }
    __syncthreads();
    for (int i = t; i < lim; i += P1_T) {
        int b = bb[i];
        bkt[gb[b] + (i - loff[b])] = pay[i];
    }
}

// ====== per-bucket histogram: off / dinv / hd0 tables =====================
__global__ void k_binhist(const u32* __restrict__ bkt, const int* __restrict__ gh,
                          const int* __restrict__ x, const float* __restrict__ emb,
                          int* __restrict__ off, float* __restrict__ dinv,
                          float4* __restrict__ hd0, int nE, int nb, int nN) {
    __shared__ int hist[256];
    int t = threadIdx.x, b = blockIdx.x;
    int base = gh[b * nb];
    int end = (b + 1 < NBK) ? gh[(b + 1) * nb] : nE;
    int sz = end - base;
    hist[t] = 0;
    __syncthreads();
    for (int i = t; i < sz; i += P2_T)
        atomicAdd(&hist[bkt[base + i] >> 17], 1);
    __syncthreads();
    int c = hist[t];
    for (int o = 1; o < 256; o <<= 1) {
        __syncthreads();
        int a = (t >= o) ? hist[t - o] : 0;
        __syncthreads();
        hist[t] += a;
    }
    __syncthreads();
    int lo = hist[t] - c;
    int d = b * 256 + t;
    off[d] = base + lo;
    if (b == NBK - 1 && t == 255) off[NBK * 256] = nE;
    if (d < nN) {
        float di = rsqrtf((float)c + 1.0f);
        dinv[d] = di;
        int xi = x[d] * 3;
        hd0[d] = make_float4(emb[xi] * di, emb[xi + 1] * di, emb[xi + 2] * di, 0.f);
    }
}

// ====== fused: bucket counting-sort -> csr + layer-1 gather + MLP chain ====
__global__ __launch_bounds__(256, 2) void k_sg1(
        const u32* __restrict__ bkt, const int* __restrict__ gh,
        const int* __restrict__ off,
        const float4* __restrict__ hd0, const float* __restrict__ dinv,
        const float* __restrict__ W1, const float* __restrict__ b1,
        const float* __restrict__ W2,
        int* __restrict__ csr, float4* __restrict__ hd2,
        int nE, int nb, int nN) {
    __shared__ int cur[256];
    __shared__ u32 stg[P2_CAP];
    int t = threadIdx.x, b = blockIdx.x;
    int base = gh[b * nb];
    int end = (b + 1 < NBK) ? gh[(b + 1) * nb] : nE;
    int sz = end - base;
    int d = b * 256 + t;
    int lo = off[d] - base;
    int n = off[d + 1] - base - lo;
    float s0 = 0.f, s1 = 0.f, s2 = 0.f;
    if (sz <= P2_CAP) {
        cur[t] = lo;
        __syncthreads();
        for (int i = t; i < sz; i += P2_T) {
            u32 v = bkt[base + i];
            int r = atomicAdd(&cur[v >> 17], 1);
            stg[r] = v & 0x1FFFFu;
        }
        __syncthreads();
        for (int i = t; i < sz; i += P2_T)
            csr[base + i] = (int)stg[i];
        if (d < nN) {
            float q0 = 0.f, q1 = 0.f, q2 = 0.f;
            float r0 = 0.f, r1 = 0.f, r2 = 0.f;
            float w0 = 0.f, w1 = 0.f, w2 = 0.f;
            int j = lo, e = lo + n;
            for (; j + 4 <= e; j += 4) {
                float4 v0 = hd0[stg[j]];
                float4 v1 = hd0[stg[j + 1]];
                float4 v2 = hd0[stg[j + 2]];
                float4 v3 = hd0[stg[j + 3]];
                s0 += v0.x; s1 += v0.y; s2 += v0.z;
                q0 += v1.x; q1 += v1.y; q2 += v1.z;
                r0 += v2.x; r1 += v2.y; r2 += v2.z;
                w0 += v3.x; w1 += v3.y; w2 += v3.z;
            }
            for (; j < e; ++j) {
                float4 v = hd0[stg[j]];
                s0 += v.x; s1 += v.y; s2 += v.z;
            }
            s0 += q0 + r0 + w0; s1 += q1 + r1 + w1; s2 += q2 + r2 + w2;
        }
    } else {
        // statistically unreachable fallback: per-thread scan-all, still sorted csr
        if (d < nN || t < 256) {
            int wpos = base + lo;
            for (int i = 0; i < sz; ++i) {
                u32 v = bkt[base + i];
                if ((int)(v >> 17) == t) {
                    csr[wpos++] = (int)(v & 0x1FFFFu);
                    float4 h = hd0[v & 0x1FFFFu];
                    s0 += h.x; s1 += h.y; s2 += h.z;
                }
            }
        }
    }
    if (d < nN) {
        float di = dinv[d];
        float4 self = hd0[d];
        float a0 = di * (s0 + self.x);
        float a1 = di * (s1 + self.y);
        float a2 = di * (s2 + self.z);
        float o0 = 0.f, o1 = 0.f, o2 = 0.f;
#pragma unroll
        for (int k = 0; k < 16; ++k) {
            float p = leaky(a0 * W1[k] + a1 * W1[16 + k] + a2 * W1[32 + k] + b1[k]);
            o0 += p * W2[k * 3 + 0];
            o1 += p * W2[k * 3 + 1];
            o2 += p * W2[k * 3 + 2];
        }
        hd2[d] = make_float4(o0 * di, o1 * di, o2 * di, 0.f);
    }
}

// ====== layer-2 gather: 16 lanes per node ==================================
__global__ void k_gather2(const int* __restrict__ off, const int* __restrict__ csr,
                          const float4* __restrict__ hd2, const float* __restrict__ dinv,
                          const float* __restrict__ b2,
                          float4* __restrict__ h2, int nN) {
    int g = blockIdx.x * blockDim.x + threadIdx.x;
    int d = g >> 4, lane = threadIdx.x & 15;
    if (d >= nN) return;
    int e0 = off[d], e1 = off[d + 1];
    float s0 = 0.f, s1 = 0.f, s2 = 0.f;
    for (int e = e0 + lane; e < e1; e += 16) {
        float4 v = hd2[csr[e]];
        s0 += v.x; s1 += v.y; s2 += v.z;
    }
    for (int o = 8; o; o >>= 1) {
        s0 += __shfl_down(s0, o, 16);
        s1 += __shfl_down(s1, o, 16);
        s2 += __shfl_down(s2, o, 16);
    }
    if (lane == 0) {
        float di = dinv[d];
        float4 self = hd2[d];
        h2[d] = make_float4(leaky(di * (s0 + self.x) + b2[0]),
                            leaky(di * (s1 + self.y) + b2[1]),
                            leaky(di * (s2 + self.z) + b2[2]), 0.f);
    }
}

// ================= per-match MLP =================
__global__ void k_mlp4(const int* __restrict__ home, const int* __restrict__ away,
                       const float4* __restrict__ h2,
                       const float* __restrict__ lw1, const float* __restrict__ lb1,
                       const float* __restrict__ lw2, const float* __restrict__ lb2,
                       const float* __restrict__ lw3, const float* __restrict__ lb3,
                       float* __restrict__ out, int nM) {
    __shared__ float s[235];
    int t = threadIdx.x;
    if (t < 96)       s[t] = lw1[t];
    else if (t < 112) s[t] = lb1[t - 96];
    else if (t < 208) s[t] = lw2[t - 112];
    else if (t < 214) s[t] = lb2[t - 208];
    else if (t < 232) s[t] = lw3[t - 214];
    else if (t < 235) s[t] = lb3[t - 232];
    __syncthreads();
    const float* sw1 = s;        const float* sb1 = s + 96;
    const float* sw2 = s + 112;  const float* sb2 = s + 208;
    const float* sw3 = s + 214;  const float* sb3 = s + 232;

    int m = blockIdx.x * blockDim.x + threadIdx.x;
    if (m >= nM) return;
    float4 zh = h2[home[m]];
    float4 za = h2[away[m]];
    float z[6] = {zh.x, zh.y, zh.z, za.x, za.y, za.z};

    float t1[16];
#pragma unroll
    for (int k = 0; k < 16; ++k) {
        float p = sb1[k];
#pragma unroll
        for (int j = 0; j < 6; ++j) p += z[j] * sw1[j * 16 + k];
        t1[k] = leaky(p);
    }
    float t2[6];
#pragma unroll
    for (int k = 0; k < 6; ++k) {
        float p = sb2[k];
#pragma unroll
        for (int j = 0; j < 16; ++j) p += t1[j] * sw2[j * 6 + k];
        t2[k] = leaky(p);
    }
#pragma unroll
    for (int k = 0; k < 3; ++k) {
        float p = sb3[k];
#pragma unroll
        for (int j = 0; j < 6; ++j) p += t2[j] * sw3[j * 3 + k];
        out[m * 3 + k] = leaky(p);
    }
}

// ================= fallback: atomic CSR build ===============
__global__ void k_hist(const int* __restrict__ dst, int* __restrict__ cnt, int nE) {
    int e = blockIdx.x * blockDim.x + threadIdx.x;
    if (e < nE) atomicAdd(&cnt[dst[e]], 1);
}
__global__ void k_prep(const int* __restrict__ off, const int* __restrict__ cnt,
                       float* __restrict__ dinv, int* __restrict__ cur, int nN) {
    int i = blockIdx.x * blockDim.x + threadIdx.x;
    if (i >= nN) return;
    dinv[i] = rsqrtf((float)cnt[i] + 1.0f);
    cur[i] = off[i];
}
__global__ void k_hd0(const int* __restrict__ x, const float* __restrict__ emb,
                      const float* __restrict__ dinv, float4* __restrict__ hd0, int nN) {
    int i = blockIdx.x * blockDim.x + threadIdx.x;
    if (i >= nN) return;
    float di = dinv[i];
    int xi = x[i] * 3;
    hd0[i] = make_float4(emb[xi] * di, emb[xi + 1] * di, emb[xi + 2] * di, 0.0f);
}
__global__ void k_place(const int* __restrict__ src, const int* __restrict__ dst,
                        int* __restrict__ cur, int* __restrict__ csr, int nE) {
    int e = blockIdx.x * blockDim.x + threadIdx.x;
    if (e >= nE) return;
    int p = atomicAdd(&cur[dst[e]], 1);
    csr[p] = src[e];
}
__global__ void k_gather1w(const int* __restrict__ off, const int* __restrict__ csr,
                           const float4* __restrict__ hd0, const float* __restrict__ dinv,
                           const float* __restrict__ W1, const float* __restrict__ b1,
                           const float* __restrict__ W2,
                           float4* __restrict__ hd2, int nN) {
    int g = blockIdx.x * blockDim.x + threadIdx.x;
    int d = g >> 6, lane = threadIdx.x & 63;
    if (d >= nN) return;
    int e0 = off[d], e1 = off[d + 1];
    float sx = 0.f, sy = 0.f, sz = 0.f;
    for (int e = e0 + lane; e < e1; e += 64) {
        float4 v = hd0[csr[e]];
        sx += v.x; sy += v.y; sz += v.z;
    }
    for (int o = 32; o; o >>= 1) {
        sx += __shfl_down(sx, o);
        sy += __shfl_down(sy, o);
        sz += __shfl_down(sz, o);
    }
    if (lane == 0) {
        float di = dinv[d];
        float4 self = hd0[d];
        float a0 = di * (sx + self.x);
        float a1 = di * (sy + self.y);
        float a2 = di * (sz + self.z);
        float o0 = 0.f, o1 = 0.f, o2 = 0.f;
#pragma unroll
        for (int k = 0; k < 16; ++k) {
            float p = leaky(a0 * W1[k] + a1 * W1[16 + k] + a2 * W1[32 + k] + b1[k]);
            o0 += p * W2[k * 3 + 0];
            o1 += p * W2[k * 3 + 1];
            o2 += p * W2[k * 3 + 2];
        }
        hd2[d] = make_float4(o0 * di, o1 * di, o2 * di, 0.0f);
    }
}

// ================= launch =================
extern "C" void kernel_launch(void* const* d_in, const int* in_sizes, int n_in,
                              void* d_out, int out_size, void* d_ws, size_t ws_size,
                              hipStream_t stream) {
    const int*   x    = (const int*)d_in[0];
    const int*   ei   = (const int*)d_in[1];
    const int*   home = (const int*)d_in[2];
    const int*   away = (const int*)d_in[3];
    const float* emb  = (const float*)d_in[4];
    const float* W1   = (const float*)d_in[5];
    const float* b1   = (const float*)d_in[6];
    const float* W2   = (const float*)d_in[7];
    const float* b2   = (const float*)d_in[8];
    const float* lw1  = (const float*)d_in[9];
    const float* lb1  = (const float*)d_in[10];
    const float* lw2  = (const float*)d_in[11];
    const float* lb2  = (const float*)d_in[12];
    const float* lw3  = (const float*)d_in[13];
    const float* lb3  = (const float*)d_in[14];
    float* out = (float*)d_out;

    const int nN = in_sizes[0];       // 100000
    const int nE = in_sizes[1] / 2;   // 5M
    const int nM = in_sizes[2];       // 1M
    const int* src = ei;
    const int* dst = ei + nE;
    const int B = 256;

    const int nb1 = (nE + P1_CHUNK - 1) / P1_CHUNK;
    const int ghN = NBK * nb1;
    const int nbs = (ghN + SBLK - 1) / SBLK;
    const int offN = NBK * 256 + 1;

    size_t need = (size_t)3 * nN * 16 + (size_t)nE * 4 * 2 + (size_t)(ghN + 1) * 4 +
                  (size_t)offN * 4 + (size_t)nN * 4 + (size_t)(nbs + 8) * 4;

    if (nN <= NBK * 256 && ws_size >= need && nbs <= SBLK) {
        char* w = (char*)d_ws;
        float4* hd0 = (float4*)w;                 w += (size_t)nN * 16;
        float4* hd2 = (float4*)w;                 w += (size_t)nN * 16;
        float4* h2  = (float4*)w;                 w += (size_t)nN * 16;
        int* csr  = (int*)w;                      w += (size_t)nE * 4;
        u32* bkt  = (u32*)w;                      w += (size_t)nE * 4;
        int* gh   = (int*)w;                      w += (size_t)(ghN + 1) * 4;
        int* off  = (int*)w;                      w += (size_t)offN * 4;
        float* dinv = (float*)w;                  w += (size_t)nN * 4;
        int* bsum = (int*)w;

        k_p1hist<<<nb1, P1_T, 0, stream>>>(dst, gh, nE, nb1);
        g_scanA<<<nbs, SBLK, 0, stream>>>(gh, gh, bsum, ghN);
        g_scanB<<<1, SBLK, 0, stream>>>(bsum, nbs);
        g_scanC<<<(ghN + B - 1) / B, B, 0, stream>>>(gh, bsum, ghN, nE);
        k_p1scatter<<<nb1, P1_T, 0, stream>>>(src, dst, gh, bkt, nE, nb1);
        k_binhist<<<NBK, P2_T, 0, stream>>>(bkt, gh, x, emb, off, dinv, hd0,
                                            nE, nb1, nN);
        k_sg1<<<NBK, P2_T, 0, stream>>>(bkt, gh, off, hd0, dinv, W1, b1, W2,
                                        csr, hd2, nE, nb1, nN);
        k_gather2<<<((size_t)nN * 16 + B - 1) / B, B, 0, stream>>>(off, csr, hd2,
                                                                   dinv, b2, h2, nN);
        k_mlp4<<<(nM + B - 1) / B, B, 0, stream>>>(home, away, h2,
                                                   lw1, lb1, lw2, lb2, lw3, lb3, out, nM);
    } else {
        // fallback: atomic CSR build
        char* w = (char*)d_ws;
        float4* hd0 = (float4*)w;                 w += (size_t)nN * 16;
        float4* hd2 = (float4*)w;                 w += (size_t)nN * 16;
        float4* h2  = (float4*)w;                 w += (size_t)nN * 16;
        int* csr  = (int*)w;                      w += (size_t)nE * 4;
        int* cnt  = (int*)w;                      w += (size_t)(nN + 1) * 4;
        int* off  = (int*)w;                      w += (size_t)(nN + 1) * 4;
        int* cur  = (int*)w;                      w += (size_t)nN * 4;
        float* dinv = (float*)w;                  w += (size_t)nN * 4;
        int* bsum = (int*)w;

        const int nTot = nN + 1;
        const int nbScan = (nTot + SBLK - 1) / SBLK;

        hipMemsetAsync(cnt, 0, (size_t)nTot * sizeof(int), stream);
        k_hist<<<(nE + B - 1) / B, B, 0, stream>>>(dst, cnt, nE);
        g_scanA<<<nbScan, SBLK, 0, stream>>>(cnt, off, bsum, nTot);
        g_scanB<<<1, SBLK, 0, stream>>>(bsum, nbScan);
        g_scanC<<<(nTot + B - 1) / B, B, 0, stream>>>(off, bsum, nTot - 1, nE);
        k_prep<<<(nN + B - 1) / B, B, 0, stream>>>(off, cnt, dinv, cur, nN);
        k_hd0<<<(nN + B - 1) / B, B, 0, stream>>>(x, emb, dinv, hd0, nN);
        k_place<<<(nE + B - 1) / B, B, 0, stream>>>(src, dst, cur, csr, nE);
        k_gather1w<<<((size_t)nN * 64 + B - 1) / B, B, 0, stream>>>(off, csr, hd0, dinv,
                                                                    W1, b1, W2, hd2, nN);
        k_gather2<<<((size_t)nN * 16 + B - 1) / B, B, 0, stream>>>(off, csr, hd2,
                                                                   dinv, b2, h2, nN);
        k_mlp4<<<(nM + B - 1) / B, B, 0, stream>>>(home, away, h2,
                                                   lw1, lb1, lw2, lb2, lw3, lb3, out, nM);
    }
}